// Round 2
// baseline (1447.933 us; speedup 1.0000x reference)
//
#include <hip/hip_runtime.h>

// GATConv with edge features, MI355X. Round 4: barrier-free, LDS-free edge kernel.
//
// R3 post-mortem: moving the GEMM to MFMA freed the VALU (38->6.5%) but time
// barely moved (645->613us) -> the kernel is LATENCY-bound: 3 barriers per tile
// serialize HBM gathers, and 50KB LDS caps occupancy at 31%.
// Fix: each wave owns 16 sorted edges, fully independent:
//   - A frags: registers, direct from edge_feat (lane (g,er): 32B at row[er],
//     k=ks*32+g*8; 16B lane requests merge into full 64B lines -> no overfetch)
//   - B frags: direct from prearranged bfrag (32KB, L1/L2-hot)
//   - epilogue runs in the MFMA C/D layout (col=lane&15, row=(lane>>4)*4+reg,
//     HW-verified in R3): lane = 4 consecutive sorted edges x 8 channels
//     (ct*16+er -> 16-lane-coalesced 64B gathers + atomics)
//   - per-wave edge metadata distributed via __shfl from lanes 0..15
// Zero LDS, zero __syncthreads.
//
// Algebra unchanged: m = src_proj[src] + edge_feat @ W_bot
//   rst = (sum_e exp(leaky(m+nh[dst])) * m) / (sum_e exp(leaky(m+nh[dst]))) + bias
// (max-free softmax: scores are O(12), exp fits fp32)

#define F 128      // F_IN
#define C 128      // H*D
#define NEG 0.2f
#define NN 50000
#define EE 800000

typedef _Float16 half8 __attribute__((ext_vector_type(8)));
typedef float f32x4 __attribute__((ext_vector_type(4)));

__device__ __forceinline__ void fma4(float4& a, float s, const float4 w) {
    a.x += s * w.x; a.y += s * w.y; a.z += s * w.z; a.w += s * w.w;
}

// ---------------- node projection: out[n][j] = sum_k in[n][k] * W[k][j]
// grid = (N/8, 2), block = 256.  y==0: src_feat@W_src_top -> src_proj ; y==1: dst_feat@W_dst -> nh
__global__ __launch_bounds__(256) void node_proj_kernel(
    const float* __restrict__ src_feat, const float* __restrict__ dst_feat,
    const float* __restrict__ W_src, const float* __restrict__ W_dst,
    float* __restrict__ src_proj, float* __restrict__ nh)
{
    const float* in; const float* W; float* out;
    if (blockIdx.y == 0) { in = src_feat; W = W_src; out = src_proj; }
    else                 { in = dst_feat; W = W_dst; out = nh; }

    __shared__ float4 xs[8 * 32];   // 8 rows x 128 floats
    const int t  = threadIdx.x;
    const int nb = blockIdx.x * 8;

    {
        int row = t >> 5, col = t & 31;
        xs[t] = ((const float4*)(in + (size_t)(nb + row) * F))[col];
    }
    __syncthreads();

    const int jq = t & 31;
    const int ng = t >> 5;
    float4 acc = make_float4(0.f, 0.f, 0.f, 0.f);
    const float4* W4 = (const float4*)W;

    #pragma unroll 4
    for (int k4 = 0; k4 < 32; ++k4) {
        float4 xv = xs[ng * 32 + k4];
        float4 w0 = W4[(4 * k4 + 0) * 32 + jq];
        float4 w1 = W4[(4 * k4 + 1) * 32 + jq];
        float4 w2 = W4[(4 * k4 + 2) * 32 + jq];
        float4 w3 = W4[(4 * k4 + 3) * 32 + jq];
        fma4(acc, xv.x, w0); fma4(acc, xv.y, w1);
        fma4(acc, xv.z, w2); fma4(acc, xv.w, w3);
    }
    ((float4*)(out + (size_t)(nb + ng) * C))[jq] = acc;
}

// ---------------- sort-by-dst machinery ----------------
__global__ __launch_bounds__(256) void hist_kernel(
    const int* __restrict__ dst_idx, int* __restrict__ deg)
{
    int e = blockIdx.x * 256 + threadIdx.x;
    if (e < EE) atomicAdd(&deg[dst_idx[e]], 1);
}

// exclusive prefix sum of deg[NN] -> cursor[NN]; single block of 1024 threads
__global__ __launch_bounds__(1024) void scan_kernel(
    const int* __restrict__ deg, int* __restrict__ cursor)
{
    __shared__ int ssum[1024];
    const int t = threadIdx.x;
    const int chunk = (NN + 1023) / 1024;   // 49
    int lo = t * chunk, hi = lo + chunk; if (hi > NN) hi = NN; if (lo > NN) lo = NN;
    int s = 0;
    for (int i = lo; i < hi; ++i) s += deg[i];
    ssum[t] = s;
    __syncthreads();
    for (int d = 1; d < 1024; d <<= 1) {
        int v = (t >= d) ? ssum[t - d] : 0;
        __syncthreads();
        ssum[t] += v;
        __syncthreads();
    }
    int run = ssum[t] - s;   // exclusive base
    for (int i = lo; i < hi; ++i) { cursor[i] = run; run += deg[i]; }
}

__global__ __launch_bounds__(256) void scatter_kernel(
    const int* __restrict__ dst_idx, int* __restrict__ cursor, int* __restrict__ elist)
{
    int e = blockIdx.x * 256 + threadIdx.x;
    if (e < EE) {
        int p = atomicAdd(&cursor[dst_idx[e]], 1);
        elist[p] = e;
    }
}

// ---------------- W_bot -> pre-arranged per-lane f16 B-fragments
// bfrag[((ct*4+ks)*64 + lane)*8 + j] = (f16) W_bot[k = ks*32 + (lane>>4)*8 + j][ct*16 + (lane&15)]
// Every wave reads its b-frag at lane-contiguous 16B -> fully coalesced, L1/L2-hot.
__global__ __launch_bounds__(256) void prep_w_kernel(
    const float* __restrict__ W_src, _Float16* __restrict__ bfrag)
{
    int i = blockIdx.x * 256 + threadIdx.x;   // 0..16383, grid 64
    int j  = i & 7;
    int lw = (i >> 3) & 63;
    int ks = (i >> 9) & 3;
    int ct = i >> 11;
    int k  = ks * 32 + (lw >> 4) * 8 + j;
    int ch = ct * 16 + (lw & 15);
    bfrag[i] = (_Float16)W_src[(size_t)(128 + k) * 128 + ch];
}

// ---------------- edge pass over SORTED edges: wave-independent MFMA tiles
// grid = E/64, block = 256 = 4 independent waves. Wave tile: 16 edges x 128 ch.
// No LDS, no __syncthreads.
__global__ __launch_bounds__(256) void edge_kernel(
    const float* __restrict__ edge_feat, const _Float16* __restrict__ bfrag,
    const float* __restrict__ src_proj, const float* __restrict__ nh,
    const int* __restrict__ src_idx, const int* __restrict__ dst_idx,
    const int* __restrict__ elist,
    float* __restrict__ num, float* __restrict__ den)
{
    const int t   = threadIdx.x;
    const int l   = t & 63;                 // lane
    const int w   = t >> 6;                 // wave in block
    const int ebw = (blockIdx.x * 4 + w) * 16;   // this wave's 16 sorted edges
    const int er  = l & 15;                 // A row / D col index
    const int g   = l >> 4;                 // k-group / D row group

    // lanes 0..15 hold the wave's edge metadata; distributed via __shfl
    int e_reg = 0, s_reg = 0, d_reg = 0;
    if (l < 16) {
        e_reg = elist[ebw + l];
        s_reg = src_idx[e_reg];
        d_reg = dst_idx[e_reg];
    }

    // ---- MFMA: D[edge][ch] for 16 edges x 128 ch, K = 128
    // A frag (same k-map as R3, HW-verified): lane holds A[er][k = ks*32 + g*8 + j]
    const float4* rp = (const float4*)(edge_feat + (size_t)__shfl(e_reg, er) * F);
    const half8*  B  = (const half8*)bfrag;

    f32x4 acc[8];
    #pragma unroll
    for (int ct = 0; ct < 8; ++ct) acc[ct] = (f32x4){0.f, 0.f, 0.f, 0.f};

    #pragma unroll
    for (int ks = 0; ks < 4; ++ks) {
        float4 f0 = rp[ks * 8 + g * 2];
        float4 f1 = rp[ks * 8 + g * 2 + 1];
        half8 a;
        a[0] = (_Float16)f0.x; a[1] = (_Float16)f0.y;
        a[2] = (_Float16)f0.z; a[3] = (_Float16)f0.w;
        a[4] = (_Float16)f1.x; a[5] = (_Float16)f1.y;
        a[6] = (_Float16)f1.z; a[7] = (_Float16)f1.w;
        #pragma unroll
        for (int ct = 0; ct < 8; ++ct) {
            half8 b = B[(ct * 4 + ks) * 64 + l];   // B[k = ks*32+g*8+j][ct*16+er]
            acc[ct] = __builtin_amdgcn_mfma_f32_16x16x32_f16(a, b, acc[ct], 0, 0, 0);
        }
    }

    // ---- epilogue in C/D layout: lane owns edges el = g*4+rg (consecutive,
    // sorted by dst) x channels ch = ct*16+er. Run-compressed atomics.
    int cur = __shfl(d_reg, g * 4);
    float nv[8], nacc[8], dacc[8];
    #pragma unroll
    for (int ct = 0; ct < 8; ++ct) {
        nv[ct]   = nh[(size_t)cur * C + ct * 16 + er];
        nacc[ct] = 0.f;
        dacc[ct] = 0.f;
    }

    #pragma unroll
    for (int rg = 0; rg < 4; ++rg) {
        const int el  = g * 4 + rg;
        const int d   = __shfl(d_reg, el);
        const int sid = __shfl(s_reg, el);
        if (d != cur) {   // uniform within each 16-lane group
            #pragma unroll
            for (int ct = 0; ct < 8; ++ct) {
                atomicAdd(num + (size_t)cur * C + ct * 16 + er, nacc[ct]);
                atomicAdd(den + (size_t)cur * C + ct * 16 + er, dacc[ct]);
                nacc[ct] = 0.f;
                dacc[ct] = 0.f;
            }
            cur = d;
            #pragma unroll
            for (int ct = 0; ct < 8; ++ct) nv[ct] = nh[(size_t)cur * C + ct * 16 + er];
        }
        const float* sprow = src_proj + (size_t)sid * C + er;
        #pragma unroll
        for (int ct = 0; ct < 8; ++ct) {
            float m = acc[ct][rg] + sprow[ct * 16];
            float s = m + nv[ct];
            s = s > 0.f ? s : NEG * s;
            float ex = __expf(s);
            nacc[ct] += ex * m;
            dacc[ct] += ex;
        }
    }
    #pragma unroll
    for (int ct = 0; ct < 8; ++ct) {
        atomicAdd(num + (size_t)cur * C + ct * 16 + er, nacc[ct]);
        atomicAdd(den + (size_t)cur * C + ct * 16 + er, dacc[ct]);
    }
}

// ---------------- finalize: out = num/den + bias  (den==0 -> bias, matches empty segment)
__global__ __launch_bounds__(256) void finalize_kernel(
    const float* __restrict__ num, const float* __restrict__ den,
    const float* __restrict__ bias, float* __restrict__ out)
{
    int i = blockIdx.x * 256 + threadIdx.x;      // float4 index
    float4 n = ((const float4*)num)[i];
    float4 d = ((const float4*)den)[i];
    float4 b = ((const float4*)bias)[i & 31];
    float4 r;
    r.x = (d.x != 0.f ? n.x / d.x : 0.f) + b.x;
    r.y = (d.y != 0.f ? n.y / d.y : 0.f) + b.y;
    r.z = (d.z != 0.f ? n.z / d.z : 0.f) + b.z;
    r.w = (d.w != 0.f ? n.w / d.w : 0.f) + b.w;
    ((float4*)out)[i] = r;
}

extern "C" void kernel_launch(void* const* d_in, const int* in_sizes, int n_in,
                              void* d_out, int out_size, void* d_ws, size_t ws_size,
                              hipStream_t stream) {
    const float* src_feat  = (const float*)d_in[0];
    const float* dst_feat  = (const float*)d_in[1];
    const float* edge_feat = (const float*)d_in[2];
    const float* W_src     = (const float*)d_in[3];   // [256][128]
    const float* W_dst     = (const float*)d_in[4];   // [128][128]
    const float* bias      = (const float*)d_in[5];   // [128]
    const int*   src_idx   = (const int*)d_in[6];
    const int*   dst_idx   = (const int*)d_in[7];
    float* out = (float*)d_out;                       // [50000][128] -> doubles as num accumulator

    const size_t NODEF = (size_t)NN * C;              // 6.4M floats

    float* ws       = (float*)d_ws;
    float* src_proj = ws;                             // 6.4M floats
    float* nh       = ws + NODEF;                     // 6.4M floats
    float* den      = ws + 2 * NODEF;                 // 6.4M floats
    int*   deg      = (int*)(ws + 3 * NODEF);         // NN ints
    int*   cursor   = deg + NN;                       // NN ints
    int*   elist    = cursor + NN;                    // EE ints
    _Float16* bfrag = (_Float16*)(elist + EE);        // 16384 f16 = 32KB (16B-aligned)

    float* num = out;  // accumulate numerator directly in d_out, finalize in place

    hipMemsetAsync(num, 0, NODEF * sizeof(float), stream);
    hipMemsetAsync(den, 0, NODEF * sizeof(float), stream);
    hipMemsetAsync(deg, 0, NN * sizeof(int), stream);

    // build dst-sorted edge list
    hist_kernel<<<(EE + 255) / 256, 256, 0, stream>>>(dst_idx, deg);
    scan_kernel<<<1, 1024, 0, stream>>>(deg, cursor);
    scatter_kernel<<<(EE + 255) / 256, 256, 0, stream>>>(dst_idx, cursor, elist);

    // W_bot -> per-lane f16 MFMA fragments (once; L1/L2-resident for the edge pass)
    prep_w_kernel<<<64, 256, 0, stream>>>(W_src, bfrag);

    // node projections (independent of the sort)
    node_proj_kernel<<<dim3(NN / 8, 2), 256, 0, stream>>>(
        src_feat, dst_feat, W_src, W_dst, src_proj, nh);

    // sorted edge pass: wave-independent MFMA tiles + fused softmax-aggregate
    edge_kernel<<<EE / 64, 256, 0, stream>>>(
        edge_feat, bfrag, src_proj, nh, src_idx, dst_idx, elist, num, den);

    finalize_kernel<<<NODEF / 4 / 256, 256, 0, stream>>>(num, den, bias, out);
}

// Round 3
// 1244.884 us; speedup vs baseline: 1.1631x; 1.1631x over previous
//
#include <hip/hip_runtime.h>

// GATConv with edge features, MI355X. Round 5: attack the hidden ~790us
// (node_proj W-streaming + single-block scan) and restore LDS-staged B frags.
//
// R4 post-mortem: three structurally different edge kernels all ~620-660us with
// every pipe idle -> edge kernel is latency/L2-bound; B-from-global put L2 hits
// on the MFMA path (R3's LDS-B was faster). Meanwhile total (1448) - edge (655)
// = ~790us of kernels hidden below the top-5 (all 5 rows are edge iterations):
// node_proj streams 128KB of W per wave from L1/L2 (~6.4GB, ~300-400us est) and
// scan is one block with 64-line TA-serialized chunk loads (~100us est).
//
// Fixes this round:
//   - node_proj: W staged in LDS (2x 32KB K-halves, <=64KB static limit),
//     32 rows/block. fp32, same accumulation order -> bit-identical numerics.
//   - scan: 49-block LDS scan + wave64 shfl scan of block sums + offset add.
//   - edge: R4 barrier-free structure + B frags staged once per block in LDS.
//
// Algebra unchanged: m = src_proj[src] + edge_feat @ W_bot
//   rst = (sum_e exp(leaky(m+nh[dst])) * m) / (sum_e exp(leaky(m+nh[dst]))) + bias
// (max-free softmax: scores are O(12), exp fits fp32)

#define F 128      // F_IN
#define C 128      // H*D
#define NEG 0.2f
#define NN 50000
#define EE 800000
#define SCAN_NB 49   // ceil(NN/1024)

typedef _Float16 half8 __attribute__((ext_vector_type(8)));
typedef float f32x4 __attribute__((ext_vector_type(4)));

__device__ __forceinline__ void fma4(float4& a, float s, const float4 w) {
    a.x += s * w.x; a.y += s * w.y; a.z += s * w.z; a.w += s * w.w;
}

// ---------------- node projection: out[n][j] = sum_k in[n][k] * W[k][j]
// grid = (ceil(NN/32), 2), block = 256.  y==0: src_feat@W_src_top -> src_proj ;
// y==1: dst_feat@W_dst -> nh.  W staged in LDS in two 64-row halves (32KB each);
// 32 node rows per block, 4 rows per thread. fp32 throughout (same numerics).
__global__ __launch_bounds__(256) void node_proj_kernel(
    const float* __restrict__ src_feat, const float* __restrict__ dst_feat,
    const float* __restrict__ W_src, const float* __restrict__ W_dst,
    float* __restrict__ src_proj, float* __restrict__ nh)
{
    const float* in; const float* W; float* out;
    if (blockIdx.y == 0) { in = src_feat; W = W_src; out = src_proj; }
    else                 { in = dst_feat; W = W_dst; out = nh; }

    __shared__ float4 Wl[2048];   // 32KB: 64 W rows x 128 floats
    __shared__ float4 xs[1024];   // 16KB: 32 node rows x 128 floats
    const int t  = threadIdx.x;
    const int nb = blockIdx.x * 32;

    // stage 32 node rows (guarded)
    #pragma unroll
    for (int i = 0; i < 4; ++i) {
        int flat = i * 256 + t;             // row*32 + col4
        int row = flat >> 5, col = flat & 31;
        xs[flat] = (nb + row < NN)
                 ? ((const float4*)(in + (size_t)(nb + row) * F))[col]
                 : make_float4(0.f, 0.f, 0.f, 0.f);
    }

    const int jq = t & 31;   // channel quad
    const int rg = t >> 5;   // row group: rows rg*4 .. rg*4+3
    float4 acc[4];
    #pragma unroll
    for (int rr = 0; rr < 4; ++rr) acc[rr] = make_float4(0.f, 0.f, 0.f, 0.f);

    const float4* Wg = (const float4*)W;

    #pragma unroll
    for (int half = 0; half < 2; ++half) {
        __syncthreads();   // first iter: covers xs staging; later: Wl readers done
        #pragma unroll
        for (int i = 0; i < 8; ++i) Wl[i * 256 + t] = Wg[half * 2048 + i * 256 + t];
        __syncthreads();

        #pragma unroll 2
        for (int k4 = 0; k4 < 16; ++k4) {
            float4 w0 = Wl[(4 * k4 + 0) * 32 + jq];
            float4 w1 = Wl[(4 * k4 + 1) * 32 + jq];
            float4 w2 = Wl[(4 * k4 + 2) * 32 + jq];
            float4 w3 = Wl[(4 * k4 + 3) * 32 + jq];
            #pragma unroll
            for (int rr = 0; rr < 4; ++rr) {
                float4 xv = xs[(rg * 4 + rr) * 32 + half * 16 + k4];
                fma4(acc[rr], xv.x, w0); fma4(acc[rr], xv.y, w1);
                fma4(acc[rr], xv.z, w2); fma4(acc[rr], xv.w, w3);
            }
        }
    }

    #pragma unroll
    for (int rr = 0; rr < 4; ++rr) {
        int row = nb + rg * 4 + rr;
        if (row < NN) ((float4*)(out + (size_t)row * C))[jq] = acc[rr];
    }
}

// ---------------- sort-by-dst machinery ----------------
__global__ __launch_bounds__(256) void hist_kernel(
    const int* __restrict__ dst_idx, int* __restrict__ deg)
{
    int e = blockIdx.x * 256 + threadIdx.x;
    if (e < EE) atomicAdd(&deg[dst_idx[e]], 1);
}

// parallel exclusive scan of deg[NN] -> cursor[NN]
// a: per-1024-block exclusive scan + block sums; b: scan of block sums; c: add offsets
__global__ __launch_bounds__(1024) void scan_a_kernel(
    const int* __restrict__ deg, int* __restrict__ cursor, int* __restrict__ bsum)
{
    __shared__ int s[1024];
    const int t = threadIdx.x;
    const int i = blockIdx.x * 1024 + t;
    int v = (i < NN) ? deg[i] : 0;
    s[t] = v;
    __syncthreads();
    for (int d = 1; d < 1024; d <<= 1) {
        int u = (t >= d) ? s[t - d] : 0;
        __syncthreads();
        s[t] += u;
        __syncthreads();
    }
    if (i < NN) cursor[i] = s[t] - v;              // exclusive within block
    if (t == 1023) bsum[blockIdx.x] = s[t];        // block total
}

__global__ __launch_bounds__(64) void scan_b_kernel(
    const int* __restrict__ bsum, int* __restrict__ boff)
{
    const int t = threadIdx.x;
    int v = (t < SCAN_NB) ? bsum[t] : 0;
    int incl = v;
    #pragma unroll
    for (int d = 1; d < 64; d <<= 1) {
        int u = __shfl_up(incl, d);
        if (t >= d) incl += u;
    }
    if (t < SCAN_NB) boff[t] = incl - v;           // exclusive block offsets
}

__global__ __launch_bounds__(1024) void scan_c_kernel(
    int* __restrict__ cursor, const int* __restrict__ boff)
{
    const int i = blockIdx.x * 1024 + threadIdx.x;
    if (i < NN) cursor[i] += boff[blockIdx.x];
}

__global__ __launch_bounds__(256) void scatter_kernel(
    const int* __restrict__ dst_idx, int* __restrict__ cursor, int* __restrict__ elist)
{
    int e = blockIdx.x * 256 + threadIdx.x;
    if (e < EE) {
        int p = atomicAdd(&cursor[dst_idx[e]], 1);
        elist[p] = e;
    }
}

// ---------------- W_bot -> pre-arranged per-lane f16 B-fragments
// bfrag[((ct*4+ks)*64 + lane)*8 + j] = (f16) W_bot[k = ks*32 + (lane>>4)*8 + j][ct*16 + (lane&15)]
__global__ __launch_bounds__(256) void prep_w_kernel(
    const float* __restrict__ W_src, _Float16* __restrict__ bfrag)
{
    int i = blockIdx.x * 256 + threadIdx.x;   // 0..16383, grid 64
    int j  = i & 7;
    int lw = (i >> 3) & 63;
    int ks = (i >> 9) & 3;
    int ct = i >> 11;
    int k  = ks * 32 + (lw >> 4) * 8 + j;
    int ch = ct * 16 + (lw & 15);
    bfrag[i] = (_Float16)W_src[(size_t)(128 + k) * 128 + ch];
}

// ---------------- edge pass over SORTED edges: wave-semi-independent MFMA tiles
// grid = E/64, block = 256 = 4 waves. Wave tile: 16 edges x 128 ch.
// B frags staged ONCE per block in 32KB LDS (single barrier); A in registers;
// epilogue in the MFMA C/D layout (col=lane&15, row=(lane>>4)*4+reg, HW-verified).
__global__ __launch_bounds__(256) void edge_kernel(
    const float* __restrict__ edge_feat, const _Float16* __restrict__ bfrag,
    const float* __restrict__ src_proj, const float* __restrict__ nh,
    const int* __restrict__ src_idx, const int* __restrict__ dst_idx,
    const int* __restrict__ elist,
    float* __restrict__ num, float* __restrict__ den)
{
    __shared__ __align__(16) half8 Blds[2048];   // 32KB, shared by all 4 waves

    const int t   = threadIdx.x;
    const int l   = t & 63;                 // lane
    const int w   = t >> 6;                 // wave in block
    const int ebw = (blockIdx.x * 4 + w) * 16;   // this wave's 16 sorted edges
    const int er  = l & 15;                 // A row / D col index
    const int g   = l >> 4;                 // k-group / D row group

    // lanes 0..15 hold the wave's edge metadata; distributed via __shfl
    int e_reg = 0, s_reg = 0, d_reg = 0;
    if (l < 16) {
        e_reg = elist[ebw + l];
        s_reg = src_idx[e_reg];
        d_reg = dst_idx[e_reg];
    }

    // prefetch this lane's A bytes (edge row er, k = ks*32 + g*8 .. +8)
    const float4* rp = (const float4*)(edge_feat + (size_t)__shfl(e_reg, er) * F);
    float4 fA[8];
    #pragma unroll
    for (int ks = 0; ks < 4; ++ks) {
        fA[2 * ks]     = rp[ks * 8 + g * 2];
        fA[2 * ks + 1] = rp[ks * 8 + g * 2 + 1];
    }

    // stage B fragments: 32KB coalesced, L2-hot, shared by all waves
    {
        const float4* bg = (const float4*)bfrag;
        float4* bl = (float4*)Blds;
        #pragma unroll
        for (int i = 0; i < 8; ++i) bl[i * 256 + t] = bg[i * 256 + t];
    }
    __syncthreads();

    // ---- MFMA: D[edge][ch] for 16 edges x 128 ch, K = 128
    f32x4 acc[8];
    #pragma unroll
    for (int ct = 0; ct < 8; ++ct) acc[ct] = (f32x4){0.f, 0.f, 0.f, 0.f};

    #pragma unroll
    for (int ks = 0; ks < 4; ++ks) {
        float4 f0 = fA[2 * ks], f1 = fA[2 * ks + 1];
        half8 a;
        a[0] = (_Float16)f0.x; a[1] = (_Float16)f0.y;
        a[2] = (_Float16)f0.z; a[3] = (_Float16)f0.w;
        a[4] = (_Float16)f1.x; a[5] = (_Float16)f1.y;
        a[6] = (_Float16)f1.z; a[7] = (_Float16)f1.w;
        #pragma unroll
        for (int ct = 0; ct < 8; ++ct) {
            half8 b = Blds[(ct * 4 + ks) * 64 + l];   // B[k=ks*32+g*8+j][ct*16+er]
            acc[ct] = __builtin_amdgcn_mfma_f32_16x16x32_f16(a, b, acc[ct], 0, 0, 0);
        }
    }

    // ---- epilogue in C/D layout: lane owns edges el = g*4+rg (consecutive,
    // sorted by dst) x channels ch = ct*16+er. Run-compressed atomics.
    int cur = __shfl(d_reg, g * 4);
    float nv[8], nacc[8], dacc[8];
    #pragma unroll
    for (int ct = 0; ct < 8; ++ct) {
        nv[ct]   = nh[(size_t)cur * C + ct * 16 + er];
        nacc[ct] = 0.f;
        dacc[ct] = 0.f;
    }

    #pragma unroll
    for (int rg = 0; rg < 4; ++rg) {
        const int el  = g * 4 + rg;
        const int d   = __shfl(d_reg, el);
        const int sid = __shfl(s_reg, el);
        if (d != cur) {   // uniform within each 16-lane group
            #pragma unroll
            for (int ct = 0; ct < 8; ++ct) {
                atomicAdd(num + (size_t)cur * C + ct * 16 + er, nacc[ct]);
                atomicAdd(den + (size_t)cur * C + ct * 16 + er, dacc[ct]);
                nacc[ct] = 0.f;
                dacc[ct] = 0.f;
            }
            cur = d;
            #pragma unroll
            for (int ct = 0; ct < 8; ++ct) nv[ct] = nh[(size_t)cur * C + ct * 16 + er];
        }
        const float* sprow = src_proj + (size_t)sid * C + er;
        #pragma unroll
        for (int ct = 0; ct < 8; ++ct) {
            float m = acc[ct][rg] + sprow[ct * 16];
            float s = m + nv[ct];
            s = s > 0.f ? s : NEG * s;
            float ex = __expf(s);
            nacc[ct] += ex * m;
            dacc[ct] += ex;
        }
    }
    #pragma unroll
    for (int ct = 0; ct < 8; ++ct) {
        atomicAdd(num + (size_t)cur * C + ct * 16 + er, nacc[ct]);
        atomicAdd(den + (size_t)cur * C + ct * 16 + er, dacc[ct]);
    }
}

// ---------------- finalize: out = num/den + bias  (den==0 -> bias, matches empty segment)
__global__ __launch_bounds__(256) void finalize_kernel(
    const float* __restrict__ num, const float* __restrict__ den,
    const float* __restrict__ bias, float* __restrict__ out)
{
    int i = blockIdx.x * 256 + threadIdx.x;      // float4 index
    float4 n = ((const float4*)num)[i];
    float4 d = ((const float4*)den)[i];
    float4 b = ((const float4*)bias)[i & 31];
    float4 r;
    r.x = (d.x != 0.f ? n.x / d.x : 0.f) + b.x;
    r.y = (d.y != 0.f ? n.y / d.y : 0.f) + b.y;
    r.z = (d.z != 0.f ? n.z / d.z : 0.f) + b.z;
    r.w = (d.w != 0.f ? n.w / d.w : 0.f) + b.w;
    ((float4*)out)[i] = r;
}

extern "C" void kernel_launch(void* const* d_in, const int* in_sizes, int n_in,
                              void* d_out, int out_size, void* d_ws, size_t ws_size,
                              hipStream_t stream) {
    const float* src_feat  = (const float*)d_in[0];
    const float* dst_feat  = (const float*)d_in[1];
    const float* edge_feat = (const float*)d_in[2];
    const float* W_src     = (const float*)d_in[3];   // [256][128]
    const float* W_dst     = (const float*)d_in[4];   // [128][128]
    const float* bias      = (const float*)d_in[5];   // [128]
    const int*   src_idx   = (const int*)d_in[6];
    const int*   dst_idx   = (const int*)d_in[7];
    float* out = (float*)d_out;                       // [50000][128] -> doubles as num accumulator

    const size_t NODEF = (size_t)NN * C;              // 6.4M floats

    float* ws       = (float*)d_ws;
    float* src_proj = ws;                             // 6.4M floats
    float* nh       = ws + NODEF;                     // 6.4M floats
    float* den      = ws + 2 * NODEF;                 // 6.4M floats
    int*   deg      = (int*)(ws + 3 * NODEF);         // NN ints
    int*   cursor   = deg + NN;                       // NN ints
    int*   elist    = cursor + NN;                    // EE ints
    _Float16* bfrag = (_Float16*)(elist + EE);        // 16384 f16 = 32KB
    int*   bsum     = (int*)(bfrag + 16384);          // 64 ints
    int*   boff     = bsum + 64;                      // 64 ints

    float* num = out;  // accumulate numerator directly in d_out, finalize in place

    hipMemsetAsync(num, 0, NODEF * sizeof(float), stream);
    hipMemsetAsync(den, 0, NODEF * sizeof(float), stream);
    hipMemsetAsync(deg, 0, NN * sizeof(int), stream);

    // build dst-sorted edge list (parallel scan)
    hist_kernel<<<(EE + 255) / 256, 256, 0, stream>>>(dst_idx, deg);
    scan_a_kernel<<<SCAN_NB, 1024, 0, stream>>>(deg, cursor, bsum);
    scan_b_kernel<<<1, 64, 0, stream>>>(bsum, boff);
    scan_c_kernel<<<SCAN_NB, 1024, 0, stream>>>(cursor, boff);
    scatter_kernel<<<(EE + 255) / 256, 256, 0, stream>>>(dst_idx, cursor, elist);

    // W_bot -> per-lane f16 MFMA fragments (once; L2-resident for the edge pass)
    prep_w_kernel<<<64, 256, 0, stream>>>(W_src, bfrag);

    // node projections (fp32, W staged in LDS; independent of the sort)
    node_proj_kernel<<<dim3((NN + 31) / 32, 2), 256, 0, stream>>>(
        src_feat, dst_feat, W_src, W_dst, src_proj, nh);

    // sorted edge pass: MFMA tiles + fused softmax-aggregate epilogue
    edge_kernel<<<EE / 64, 256, 0, stream>>>(
        edge_feat, bfrag, src_proj, nh, src_idx, dst_idx, elist, num, den);

    finalize_kernel<<<NODEF / 4 / 256, 256, 0, stream>>>(num, den, bias, out);
}